// Round 9
// baseline (813.953 us; speedup 1.0000x reference)
//
#include <hip/hip_runtime.h>
#include <math.h>

typedef __attribute__((ext_vector_type(8))) short short8;
typedef __attribute__((ext_vector_type(4))) float f32x4;

#define HW    4096
#define B_    32
#define CIN   256
#define HID   128
#define A_    9
#define NCLS  20
#define M_    4096
#define NBOX  64
#define S_TOT (B_*HW)

// ---- output layout (floats) ----
#define PROP_SIZE (B_*A_*HW*4)
#define IOU_OFF   ((size_t)PROP_SIZE)
#define IOU_SIZE  ((size_t)B_*A_*HW*NBOX)
#define CONF_LOSS_OFF (IOU_OFF + IOU_SIZE)
#define REG_LOSS_OFF  (CONF_LOSS_OFF + 1)
#define CLS_OFF       (CONF_LOSS_OFF + 2)

// ---- workspace layout (float offsets) ----
#define WS_W1A_F 0                          // 32768 ushort (W1, A-frag order [ks][m])
#define WS_W2A_F 16384                      // 10240 ushort (W2 padded to 80 rows, [ks][m])
#define WS_B2P   21504                      // 80 floats (b2 padded)
#define WS_CNT   21584                      // 1 int: conv-block completion counter
#define WS_CONF  21632                      // B*A*HW raw conf
#define WS_OFF4  (WS_CONF + B_*A_*HW)       // B*A*HW float4 offsets
#define WS_CLS   (WS_OFF4 + B_*A_*HW*4)     // 20 planes of B*HW raw class scores

#define NCONV 2048
#define NIOU  2304                          // 9216 wave-chunks / 4 waves
#define NBLK  (NCONV + NIOU)                // 4352
#define NTAIL 321
#define NGRID (NBLK + NTAIL)                // 4673

__device__ __forceinline__ unsigned short f2bf(float x) {   // RNE float->bf16
    unsigned int u = __float_as_uint(x);
    unsigned int r = (u + 0x7FFFu + ((u >> 16) & 1u)) >> 16;
    return (unsigned short)r;
}
__device__ __forceinline__ float vrcp(float x) {            // v_rcp_f32, ~1ulp
    float r; asm("v_rcp_f32 %0, %1" : "=v"(r) : "v"(x)); return r;
}
__device__ __forceinline__ float vexp2(float x) {           // v_exp_f32 = 2^x
    float r; asm("v_exp_f32 %0, %1" : "=v"(r) : "v"(x)); return r;
}
__device__ __forceinline__ float fexp(float x)  { return vexp2(x * 1.44269504f); }
__device__ __forceinline__ float fsig(float x)  { return vrcp(1.0f + fexp(-x)); }

// LDS byte addr for FbT[col][k] (col<64, k<256, bf16), XOR-swizzled, b128-aligned
__device__ __forceinline__ int fbt_addr(int col, int k) {
    return col * 512 + ((k * 2) ^ ((col & 31) << 4));
}
// LDS byte addr for HbT[col][k] (col<64, k<128, bf16) — overlays FbT region (base 0)
__device__ __forceinline__ int hbt_addr(int col, int k) {
    return col * 256 + ((k * 2) ^ ((col & 7) << 4));
}

// Pack W1 (128x256) and W2 (65x128 -> 80x128 zero-pad) into MFMA A-fragment order,
// fragment index = ks*NM + m (ks-major: 8KB window shared by the waves via L1).
// Also zeroes the conv completion counter (stream order: prep < fused).
__global__ __launch_bounds__(256) void prep_weights(
    const float* __restrict__ W1, const float* __restrict__ W2,
    const float* __restrict__ b2, float* __restrict__ ws)
{
    int t = blockIdx.x * 256 + threadIdx.x;
    unsigned short* W1a = (unsigned short*)(ws + WS_W1A_F);
    unsigned short* W2a = (unsigned short*)(ws + WS_W2A_F);
    if (t < 32768) {
        int j = t & 7, l = (t >> 3) & 63, f = t >> 9;   // f = ks*8 + m
        int ks = f >> 3, m = f & 7;
        int row = m * 16 + (l & 15);
        int k   = ks * 32 + (l >> 4) * 8 + j;
        W1a[t] = f2bf(W1[row * CIN + k]);
    } else if (t < 32768 + 10240) {
        int u = t - 32768;
        int j = u & 7, l = (u >> 3) & 63, f = u >> 9;   // f = ks*5 + m
        int ks = f / 5, m = f % 5;
        int row = m * 16 + (l & 15);
        int k   = ks * 32 + (l >> 4) * 8 + j;
        W2a[u] = f2bf(row < 65 ? W2[row * HID + k] : 0.0f);
    } else if (t < 32768 + 10240 + 80) {
        int v = t - 43008;
        ws[WS_B2P + v] = (v < 65) ? b2[v] : 0.0f;
    } else if (t == 43100) {
        *(int*)(ws + WS_CNT) = 0;
    }
}

// Role-split fused kernel:
//   bid < 4096: parity split — even = conv tile, odd = IoU chunk block
//   bid in [4096, 4352): extra IoU blocks
//   bid in [4352, 4673): tail blocks — spin until all 2048 conv blocks done
//     (device-scope counter), then cls gather / losses. Overlaps iou drain.
__global__ __launch_bounds__(256, 4) void fused_kernel(
    const float* __restrict__ features, const float* __restrict__ grid,
    const float* __restrict__ anc,      const float* __restrict__ b1,
    const float* __restrict__ bboxes,   const float* __restrict__ GT_offsets,
    const int* __restrict__ pos_idx,    const int* __restrict__ neg_idx,
    float* __restrict__ ws,             float* __restrict__ dout)
{
    const int bid = blockIdx.x;
    const int tid = threadIdx.x;
    const int wv  = tid >> 6;
    const int ln  = tid & 63;
    int* const cnt = (int*)(ws + WS_CNT);

    // ---------------- tail role ----------------
    if (bid >= NBLK) {
        const int t_role = bid - NBLK;
        if (tid == 0) {
            while (__hip_atomic_load(cnt, __ATOMIC_ACQUIRE, __HIP_MEMORY_SCOPE_AGENT) < NCONV)
                __builtin_amdgcn_s_sleep(8);
        }
        __syncthreads();

        if (t_role < 320) {
            int t = t_role * 256 + tid;            // 81920 = 320*256 exactly
            int m = t / NCLS, c = t % NCLS;
            int ip = pos_idx[m];
            int bb = ip / (A_ * HW);
            int hw = ip & (HW - 1);
            dout[CLS_OFF + t] = ws[WS_CLS + (size_t)c * S_TOT + bb * HW + hw];
            return;
        }
        float conf_sum = 0.0f, reg_sum = 0.0f;
        for (int m = tid; m < M_; m += 256) {
            int ip = pos_idx[m], in_ = neg_idx[m];
            float cp = fsig(ws[WS_CONF + ip]);
            float cn = fsig(ws[WS_CONF + in_]);
            conf_sum += (cp - 1.0f) * (cp - 1.0f) + cn * cn;
            float4 off = ((const float4*)(ws + WS_OFF4))[ip];
            float d0 = off.x - GT_offsets[4 * m + 0];
            float d1 = off.y - GT_offsets[4 * m + 1];
            float d2 = off.z - GT_offsets[4 * m + 2];
            float d3 = off.w - GT_offsets[4 * m + 3];
            reg_sum += d0 * d0 + d1 * d1 + d2 * d2 + d3 * d3;
        }
        #pragma unroll
        for (int off = 32; off > 0; off >>= 1) {
            conf_sum += __shfl_down(conf_sum, off);
            reg_sum  += __shfl_down(reg_sum, off);
        }
        __shared__ float rc[4], rr[4];
        if ((tid & 63) == 0) { rc[wv] = conf_sum; rr[wv] = reg_sum; }
        __syncthreads();
        if (tid == 0) {
            dout[CONF_LOSS_OFF] = (rc[0] + rc[1] + rc[2] + rc[3]) / (2.0f * M_);
            dout[REG_LOSS_OFF]  = (rr[0] + rr[1] + rr[2] + rr[3]) / (float)M_;
        }
        return;
    }

    bool is_conv; int idx;
    if (bid < 2 * NCONV) { is_conv = (bid & 1) == 0; idx = bid >> 1; }
    else                 { is_conv = false;          idx = NCONV + (bid - 2 * NCONV); }

    // ---------------- IoU role ----------------
    if (!is_conv) {
        const int cid = idx * 4 + wv;                 // 0..9215
        const int b   = cid / (A_ * 32);
        const int rem = cid % (A_ * 32);
        const int a   = rem / 32;
        const int hw0 = (rem % 32) * 128;
        const int hwi = ln >> 4;
        const int nq  = ln & 15;

        float bx0[4], by0[4], bx2[4], by2[4], areab[4];
        #pragma unroll
        for (int j = 0; j < 4; ++j) {
            const float* bb = bboxes + ((size_t)b * NBOX + nq * 4 + j) * 5;
            bx0[j] = bb[0]; by0[j] = bb[1]; bx2[j] = bb[2]; by2[j] = bb[3];
            areab[j] = (bx2[j] - bx0[j]) * (by2[j] - by0[j]);
        }
        const float hwd = 0.5f * anc[2 * a], hh = 0.5f * anc[2 * a + 1];
        const float ap  = 4.0f * hwd * hh;
        const float2* gp = (const float2*)grid + (size_t)b * HW;
        float* ioub = dout + IOU_OFF + (size_t)(b * A_ + a) * HW * NBOX;
        #pragma unroll 4
        for (int t = 0; t < 32; ++t) {
            const int hw = hw0 + t * 4 + hwi;
            const float2 g = gp[hw];
            f32x4 res;
            #pragma unroll
            for (int j = 0; j < 4; ++j) {
                float dx = fmaxf(fminf(bx2[j] - g.x, hwd) - fmaxf(bx0[j] - g.x, -hwd), 0.0f);
                float dy = fmaxf(fminf(by2[j] - g.y, hh ) - fmaxf(by0[j] - g.y, -hh ), 0.0f);
                float inter = dx * dy;
                res[j] = inter * vrcp(ap + areab[j] - inter);
            }
            // wave store = 1KB contiguous (addr = base + ln*16)
            __builtin_nontemporal_store(
                res, (f32x4*)(ioub + ((size_t)hw) * NBOX + nq * 4));
        }
        return;
    }

    // ---------------- conv role ----------------
    __shared__ __align__(16) char smem[32768];   // FbT 32KB; HbT/Ot overlay

    const int s0  = idx * 64;
    const int b   = s0 >> 12;
    const int hw0 = s0 & (HW - 1);
    const int col = tid & 63;
    const int kg  = ln >> 4;           // k-group 0..3
    const int colg = wv * 16 + (ln & 15);

    // ---- stage F tile (256 x 64): float4 loads + in-register 4x4 lane
    // transpose (shfl_xor 32/16 butterfly) -> bf16 -> swizzled FbT ----
    {
        const int g = ln >> 4, q = ln & 15;
        const float* fb = features + (size_t)b * CIN * HW + hw0;
        #pragma unroll
        for (int i = 0; i < 16; ++i) {
            const int k = i * 16 + wv * 4 + g;                     // 4 rows/instr
            const float4 v = *(const float4*)(fb + (size_t)k * HW + 4 * q);
            float t0 = __shfl_xor(v.x, 32), t1 = __shfl_xor(v.y, 32);
            float t2 = __shfl_xor(v.z, 32), t3 = __shfl_xor(v.w, 32);
            const bool h2 = (g & 2) != 0;
            float p0 = h2 ? t2 : v.x, p1 = h2 ? t3 : v.y;
            float p2 = h2 ? v.z : t0, p3 = h2 ? v.w : t1;
            float u0 = __shfl_xor(p0, 16), u1 = __shfl_xor(p1, 16);
            float u2 = __shfl_xor(p2, 16), u3 = __shfl_xor(p3, 16);
            const bool h1 = (g & 1) != 0;
            float c0 = h1 ? u1 : p0, c1 = h1 ? p1 : u0;
            float c2 = h1 ? u3 : p2, c3 = h1 ? p3 : u2;
            const int k0 = i * 16 + wv * 4;
            uint2 pk;
            pk.x = (unsigned)f2bf(c0) | ((unsigned)f2bf(c1) << 16);
            pk.y = (unsigned)f2bf(c2) | ((unsigned)f2bf(c3) << 16);
            *(uint2*)(smem + fbt_addr(4 * q + g, k0)) = pk;
        }
    }
    __syncthreads();

    // ---- GEMM1: hdn[128][64] = W1 @ F ----
    const unsigned short* W1a = (const unsigned short*)(ws + WS_W1A_F);
    f32x4 acc[8];
    #pragma unroll
    for (int m = 0; m < 8; ++m) acc[m] = (f32x4){0.f, 0.f, 0.f, 0.f};
    #pragma unroll
    for (int ks = 0; ks < 8; ++ks) {
        short8 bf = *(const short8*)(smem + fbt_addr(colg, ks * 32 + kg * 8));
        #pragma unroll
        for (int m = 0; m < 8; ++m) {
            short8 af = *(const short8*)(W1a + ((ks * 8 + m) * 64 + ln) * 8);
            acc[m] = __builtin_amdgcn_mfma_f32_16x16x32_bf16(af, bf, acc[m], 0, 0, 0);
        }
    }
    __syncthreads();   // all FbT reads done before HbT overlays the region

    // ---- bias + leaky relu, bf16, write HbT (swizzled, overlays FbT) ----
    #pragma unroll
    for (int m = 0; m < 8; ++m) {
        float4 bv = *(const float4*)(b1 + m * 16 + kg * 4);
        float v0 = acc[m][0] + bv.x, v1 = acc[m][1] + bv.y;
        float v2 = acc[m][2] + bv.z, v3 = acc[m][3] + bv.w;
        v0 = v0 > 0.f ? v0 : 0.01f * v0;  v1 = v1 > 0.f ? v1 : 0.01f * v1;
        v2 = v2 > 0.f ? v2 : 0.01f * v2;  v3 = v3 > 0.f ? v3 : 0.01f * v3;
        unsigned int lo = (unsigned int)f2bf(v0) | ((unsigned int)f2bf(v1) << 16);
        unsigned int hi = (unsigned int)f2bf(v2) | ((unsigned int)f2bf(v3) << 16);
        *(uint2*)(smem + hbt_addr(colg, m * 16 + kg * 4)) = make_uint2(lo, hi);
    }
    __syncthreads();

    // ---- GEMM2: out[80][64] = W2pad @ hdn ----
    const unsigned short* W2a = (const unsigned short*)(ws + WS_W2A_F);
    f32x4 a2[5];
    #pragma unroll
    for (int m = 0; m < 5; ++m) a2[m] = (f32x4){0.f, 0.f, 0.f, 0.f};
    #pragma unroll
    for (int ks = 0; ks < 4; ++ks) {
        short8 bf = *(const short8*)(smem + hbt_addr(colg, ks * 32 + kg * 8));
        #pragma unroll
        for (int m = 0; m < 5; ++m) {
            short8 af = *(const short8*)(W2a + ((ks * 5 + m) * 64 + ln) * 8);
            a2[m] = __builtin_amdgcn_mfma_f32_16x16x32_bf16(af, bf, a2[m], 0, 0, 0);
        }
    }
    __syncthreads();   // all HbT reads done before Ot overlays the region

    // ---- stage out tile to LDS (fp32, stride 65) ----
    float* Ot = (float*)smem;
    const float* b2p = ws + WS_B2P;
    #pragma unroll
    for (int m = 0; m < 5; ++m) {
        float4 bv = *(const float4*)(b2p + m * 16 + kg * 4);
        #pragma unroll
        for (int i = 0; i < 4; ++i)
            Ot[(m * 16 + kg * 4 + i) * 65 + colg] = a2[m][i] + ((const float*)&bv)[i];
    }
    __syncthreads();

    // ---- epilogue: wave 0 conf, waves 1-2 offsets+proposals, wave 3 cls ----
    const float* OtC = (const float*)smem;
    const int hw = hw0 + col;
    if (wv == 0) {
        #pragma unroll
        for (int a = 0; a < A_; ++a)
            ws[WS_CONF + (size_t)(b * A_ + a) * HW + hw] = OtC[a * 65 + col];
    } else if (wv == 3) {
        #pragma unroll
        for (int c = 0; c < NCLS; ++c)
            ws[WS_CLS + (size_t)c * S_TOT + b * HW + hw] = OtC[(45 + c) * 65 + col];
    } else {
        const float2 g2 = ((const float2*)grid)[(size_t)b * HW + hw];
        int a0 = (wv == 1) ? 0 : 4;
        int a1 = (wv == 1) ? 4 : 9;
        for (int a = a0; a < a1; ++a) {
            float t0 = OtC[(A_ + 4 * a + 0) * 65 + col];
            float t1 = OtC[(A_ + 4 * a + 1) * 65 + col];
            float t2 = OtC[(A_ + 4 * a + 2) * 65 + col];
            float t3 = OtC[(A_ + 4 * a + 3) * 65 + col];
            t0 = fsig(t0) - 0.5f;
            t1 = fsig(t1) - 0.5f;
            size_t odx = (size_t)(b * A_ + a) * HW + hw;
            ((float4*)(ws + WS_OFF4))[odx] = make_float4(t0, t1, t2, t3);
            float aw = anc[2 * a], ah = anc[2 * a + 1];
            float xc = g2.x + t0, yc = g2.y + t1;
            float wn = aw * fexp(t2), hn = ah * fexp(t3);
            f32x4 prop = {xc - 0.5f * wn, yc - 0.5f * hn,
                          xc + 0.5f * wn, yc + 0.5f * hn};
            __builtin_nontemporal_store(prop, (f32x4*)dout + odx);
        }
    }

    // ---- publish completion (release) for tail blocks ----
    __threadfence();
    __syncthreads();
    if (tid == 0)
        __hip_atomic_fetch_add(cnt, 1, __ATOMIC_RELEASE, __HIP_MEMORY_SCOPE_AGENT);
}

extern "C" void kernel_launch(void* const* d_in, const int* in_sizes, int n_in,
                              void* d_out, int out_size, void* d_ws, size_t ws_size,
                              hipStream_t stream) {
    const float* features    = (const float*)d_in[0];
    const float* grid        = (const float*)d_in[1];
    const float* anc         = (const float*)d_in[2];
    const float* bboxes      = (const float*)d_in[3];
    const float* GT_offsets  = (const float*)d_in[4];
    const float* W1          = (const float*)d_in[6];
    const float* b1          = (const float*)d_in[7];
    const float* W2          = (const float*)d_in[8];
    const float* b2          = (const float*)d_in[9];
    const int*   pos_idx     = (const int*)d_in[10];
    const int*   neg_idx     = (const int*)d_in[11];
    float* out = (float*)d_out;
    float* ws  = (float*)d_ws;

    prep_weights<<<169, 256, 0, stream>>>(W1, W2, b2, ws);
    fused_kernel<<<NGRID, 256, 0, stream>>>(features, grid, anc, b1, bboxes,
                                            GT_offsets, pos_idx, neg_idx, ws, out);
}

// Round 10
// 118.906 us; speedup vs baseline: 6.8454x; 6.8454x over previous
//
#include <hip/hip_runtime.h>
#include <math.h>

typedef __attribute__((ext_vector_type(8))) short short8;
typedef __attribute__((ext_vector_type(4))) float f32x4;

#define HW    4096
#define B_    32
#define CIN   256
#define HID   128
#define A_    9
#define NCLS  20
#define M_    4096
#define NBOX  64
#define S_TOT (B_*HW)

// ---- output layout (floats) ----
#define PROP_SIZE (B_*A_*HW*4)
#define IOU_OFF   ((size_t)PROP_SIZE)
#define IOU_SIZE  ((size_t)B_*A_*HW*NBOX)
#define CONF_LOSS_OFF (IOU_OFF + IOU_SIZE)
#define REG_LOSS_OFF  (CONF_LOSS_OFF + 1)
#define CLS_OFF       (CONF_LOSS_OFF + 2)

// ---- workspace layout (float offsets) ----
#define WS_W1A_F 0                          // 32768 ushort (W1, A-frag order [ks][m])
#define WS_W2A_F 16384                      // 10240 ushort (W2 padded to 80 rows, [ks][m])
#define WS_B2P   21504                      // 80 floats (b2 padded)

#define NCONV 2048
#define NIOU  2304                          // 9216 wave-chunks / 4 waves
#define NBLK  (NCONV + NIOU)                // 4352
#define NGATH 128                           // 64 pos + 64 neg sample blocks
#define NGRID (NBLK + NGATH)                // 4480

__device__ __forceinline__ unsigned short f2bf(float x) {   // RNE float->bf16
    unsigned int u = __float_as_uint(x);
    unsigned int r = (u + 0x7FFFu + ((u >> 16) & 1u)) >> 16;
    return (unsigned short)r;
}
__device__ __forceinline__ float vrcp(float x) {            // v_rcp_f32, ~1ulp
    float r; asm("v_rcp_f32 %0, %1" : "=v"(r) : "v"(x)); return r;
}
__device__ __forceinline__ float vexp2(float x) {           // v_exp_f32 = 2^x
    float r; asm("v_exp_f32 %0, %1" : "=v"(r) : "v"(x)); return r;
}
__device__ __forceinline__ float fexp(float x)  { return vexp2(x * 1.44269504f); }
__device__ __forceinline__ float fsig(float x)  { return vrcp(1.0f + fexp(-x)); }

// LDS byte addr for FbT[col][k] (col<64, k<256, bf16), XOR-swizzled, b128-aligned
__device__ __forceinline__ int fbt_addr(int col, int k) {
    return col * 512 + ((k * 2) ^ ((col & 31) << 4));
}
// LDS byte addr for HbT[col][k] (col<64, k<128, bf16) — overlays FbT region (base 0)
__device__ __forceinline__ int hbt_addr(int col, int k) {
    return col * 256 + ((k * 2) ^ ((col & 7) << 4));
}

// Pack W1 (128x256) and W2 (65x128 -> 80x128 zero-pad) into MFMA A-fragment order,
// fragment index = ks*NM + m. Also zeroes the two loss accumulators in dout
// (runs before fused_kernel every replay; gather blocks atomicAdd into them).
__global__ __launch_bounds__(256) void prep_weights(
    const float* __restrict__ W1, const float* __restrict__ W2,
    const float* __restrict__ b2, float* __restrict__ ws,
    float* __restrict__ dout)
{
    int t = blockIdx.x * 256 + threadIdx.x;
    unsigned short* W1a = (unsigned short*)(ws + WS_W1A_F);
    unsigned short* W2a = (unsigned short*)(ws + WS_W2A_F);
    if (t < 32768) {
        int j = t & 7, l = (t >> 3) & 63, f = t >> 9;   // f = ks*8 + m
        int ks = f >> 3, m = f & 7;
        int row = m * 16 + (l & 15);
        int k   = ks * 32 + (l >> 4) * 8 + j;
        W1a[t] = f2bf(W1[row * CIN + k]);
    } else if (t < 32768 + 10240) {
        int u = t - 32768;
        int j = u & 7, l = (u >> 3) & 63, f = u >> 9;   // f = ks*5 + m
        int ks = f / 5, m = f % 5;
        int row = m * 16 + (l & 15);
        int k   = ks * 32 + (l >> 4) * 8 + j;
        W2a[u] = f2bf(row < 65 ? W2[row * HID + k] : 0.0f);
    } else if (t < 32768 + 10240 + 80) {
        int v = t - 43008;
        ws[WS_B2P + v] = (v < 65) ? b2[v] : 0.0f;
    } else if (t == 43100) {
        dout[CONF_LOSS_OFF] = 0.0f;
        dout[REG_LOSS_OFF]  = 0.0f;
    }
}

// Three independent roles, no cross-role sync:
//   bid < 4096: parity — even = conv tile (proposals only), odd = IoU chunk
//   [4096, 4352): extra IoU blocks
//   [4352, 4480): gather-conv — recompute conf/off/cls at sampled indices,
//     emit class_scores + loss atomics. Reads only inputs; fully independent.
__global__ __launch_bounds__(256, 4) void fused_kernel(
    const float* __restrict__ features, const float* __restrict__ grid,
    const float* __restrict__ anc,      const float* __restrict__ b1,
    const float* __restrict__ bboxes,   const float* __restrict__ GT_offsets,
    const int* __restrict__ pos_idx,    const int* __restrict__ neg_idx,
    float* __restrict__ ws,             float* __restrict__ dout)
{
    const int bid = blockIdx.x;
    const int tid = threadIdx.x;
    const int wv  = tid >> 6;
    const int ln  = tid & 63;

    __shared__ __align__(16) char smem[32768];   // FbT 32KB; HbT/Ot overlay
    const unsigned short* W1a = (const unsigned short*)(ws + WS_W1A_F);
    const unsigned short* W2a = (const unsigned short*)(ws + WS_W2A_F);
    const float* b2p = ws + WS_B2P;
    const int kg   = ln >> 4;
    const int colg = wv * 16 + (ln & 15);

    // ---------------- gather-conv role ----------------
    if (bid >= NBLK) {
        const int g   = bid - NBLK;                  // 0..127
        const bool pos = g < 64;
        const int m0  = (pos ? g : g - 64) * 64;
        const int* idxlist = pos ? pos_idx : neg_idx;

        // stage: thread = (col = tid&63, ks4 = tid>>6); 64 k-values per thread,
        // scalar loads (scattered b,hw per col), bf16-pack into swizzled FbT.
        {
            const int col = tid & 63;
            const int ip  = idxlist[m0 + col];
            const int ba  = ip >> 12;                // b*9 + a
            const int b   = ba / 9;
            const int hw  = ip & (HW - 1);
            const float* fb = features + (size_t)b * CIN * HW + hw;
            const int k0 = (tid >> 6) * 64;
            #pragma unroll
            for (int kk = 0; kk < 64; kk += 2) {
                float x0 = fb[(size_t)(k0 + kk)     * HW];
                float x1 = fb[(size_t)(k0 + kk + 1) * HW];
                unsigned pk = (unsigned)f2bf(x0) | ((unsigned)f2bf(x1) << 16);
                *(unsigned*)(smem + fbt_addr(col, k0 + kk)) = pk;
            }
        }
        __syncthreads();

        // GEMM1 (identical to conv role)
        f32x4 acc[8];
        #pragma unroll
        for (int m = 0; m < 8; ++m) acc[m] = (f32x4){0.f, 0.f, 0.f, 0.f};
        #pragma unroll
        for (int ks = 0; ks < 8; ++ks) {
            short8 bf = *(const short8*)(smem + fbt_addr(colg, ks * 32 + kg * 8));
            #pragma unroll
            for (int m = 0; m < 8; ++m) {
                short8 af = *(const short8*)(W1a + ((ks * 8 + m) * 64 + ln) * 8);
                acc[m] = __builtin_amdgcn_mfma_f32_16x16x32_bf16(af, bf, acc[m], 0, 0, 0);
            }
        }
        __syncthreads();
        #pragma unroll
        for (int m = 0; m < 8; ++m) {
            float4 bv = *(const float4*)(b1 + m * 16 + kg * 4);
            float v0 = acc[m][0] + bv.x, v1 = acc[m][1] + bv.y;
            float v2 = acc[m][2] + bv.z, v3 = acc[m][3] + bv.w;
            v0 = v0 > 0.f ? v0 : 0.01f * v0;  v1 = v1 > 0.f ? v1 : 0.01f * v1;
            v2 = v2 > 0.f ? v2 : 0.01f * v2;  v3 = v3 > 0.f ? v3 : 0.01f * v3;
            unsigned lo = (unsigned)f2bf(v0) | ((unsigned)f2bf(v1) << 16);
            unsigned hi = (unsigned)f2bf(v2) | ((unsigned)f2bf(v3) << 16);
            *(uint2*)(smem + hbt_addr(colg, m * 16 + kg * 4)) = make_uint2(lo, hi);
        }
        __syncthreads();
        f32x4 a2[5];
        #pragma unroll
        for (int m = 0; m < 5; ++m) a2[m] = (f32x4){0.f, 0.f, 0.f, 0.f};
        #pragma unroll
        for (int ks = 0; ks < 4; ++ks) {
            short8 bf = *(const short8*)(smem + hbt_addr(colg, ks * 32 + kg * 8));
            #pragma unroll
            for (int m = 0; m < 5; ++m) {
                short8 af = *(const short8*)(W2a + ((ks * 5 + m) * 64 + ln) * 8);
                a2[m] = __builtin_amdgcn_mfma_f32_16x16x32_bf16(af, bf, a2[m], 0, 0, 0);
            }
        }
        __syncthreads();
        float* Ot = (float*)smem;
        #pragma unroll
        for (int m = 0; m < 5; ++m) {
            float4 bv = *(const float4*)(b2p + m * 16 + kg * 4);
            #pragma unroll
            for (int i = 0; i < 4; ++i)
                Ot[(m * 16 + kg * 4 + i) * 65 + colg] = a2[m][i] + ((const float*)&bv)[i];
        }
        __syncthreads();

        // epilogue: wave 0 handles all 64 sampled columns (lane = col)
        if (wv == 0) {
            const float* OtC = (const float*)smem;
            const int ip = idxlist[m0 + ln];
            const int a  = (ip >> 12) % 9;
            float conf = OtC[a * 65 + ln];
            float sc = fsig(conf);
            float gt = pos ? 1.0f : 0.0f;
            float closs = (sc - gt) * (sc - gt);
            float rloss = 0.0f;
            if (pos) {
                float t0 = fsig(OtC[(A_ + 4 * a + 0) * 65 + ln]) - 0.5f;
                float t1 = fsig(OtC[(A_ + 4 * a + 1) * 65 + ln]) - 0.5f;
                float t2 = OtC[(A_ + 4 * a + 2) * 65 + ln];
                float t3 = OtC[(A_ + 4 * a + 3) * 65 + ln];
                float4 gto = *(const float4*)(GT_offsets + 4 * (m0 + ln));
                float d0 = t0 - gto.x, d1 = t1 - gto.y;
                float d2 = t2 - gto.z, d3 = t3 - gto.w;
                rloss = d0 * d0 + d1 * d1 + d2 * d2 + d3 * d3;
                #pragma unroll
                for (int c = 0; c < NCLS; ++c)
                    dout[CLS_OFF + (size_t)(m0 + ln) * NCLS + c] = OtC[(45 + c) * 65 + ln];
            }
            #pragma unroll
            for (int off = 32; off > 0; off >>= 1) {
                closs += __shfl_down(closs, off);
                rloss += __shfl_down(rloss, off);
            }
            if (ln == 0) {
                atomicAdd(dout + CONF_LOSS_OFF, closs / (2.0f * M_));
                if (pos) atomicAdd(dout + REG_LOSS_OFF, rloss / (float)M_);
            }
        }
        return;
    }

    bool is_conv; int idx;
    if (bid < 2 * NCONV) { is_conv = (bid & 1) == 0; idx = bid >> 1; }
    else                 { is_conv = false;          idx = NCONV + (bid - 2 * NCONV); }

    // ---------------- IoU role ----------------
    if (!is_conv) {
        const int cid = idx * 4 + wv;                 // 0..9215
        const int b   = cid / (A_ * 32);
        const int rem = cid % (A_ * 32);
        const int a   = rem / 32;
        const int hw0 = (rem % 32) * 128;
        const int hwi = ln >> 4;
        const int nq  = ln & 15;

        float bx0[4], by0[4], bx2[4], by2[4], areab[4];
        #pragma unroll
        for (int j = 0; j < 4; ++j) {
            const float* bb = bboxes + ((size_t)b * NBOX + nq * 4 + j) * 5;
            bx0[j] = bb[0]; by0[j] = bb[1]; bx2[j] = bb[2]; by2[j] = bb[3];
            areab[j] = (bx2[j] - bx0[j]) * (by2[j] - by0[j]);
        }
        const float hwd = 0.5f * anc[2 * a], hh = 0.5f * anc[2 * a + 1];
        const float ap  = 4.0f * hwd * hh;
        const float2* gp = (const float2*)grid + (size_t)b * HW;
        float* ioub = dout + IOU_OFF + (size_t)(b * A_ + a) * HW * NBOX;
        #pragma unroll 4
        for (int t = 0; t < 32; ++t) {
            const int hw = hw0 + t * 4 + hwi;
            const float2 g = gp[hw];
            f32x4 res;
            #pragma unroll
            for (int j = 0; j < 4; ++j) {
                float dx = fmaxf(fminf(bx2[j] - g.x, hwd) - fmaxf(bx0[j] - g.x, -hwd), 0.0f);
                float dy = fmaxf(fminf(by2[j] - g.y, hh ) - fmaxf(by0[j] - g.y, -hh ), 0.0f);
                float inter = dx * dy;
                res[j] = inter * vrcp(ap + areab[j] - inter);
            }
            __builtin_nontemporal_store(
                res, (f32x4*)(ioub + ((size_t)hw) * NBOX + nq * 4));
        }
        return;
    }

    // ---------------- conv role (proposals only) ----------------
    const int s0  = idx * 64;
    const int b   = s0 >> 12;
    const int hw0 = s0 & (HW - 1);
    const int col = tid & 63;

    {
        const int g = ln >> 4, q = ln & 15;
        const float* fb = features + (size_t)b * CIN * HW + hw0;
        #pragma unroll
        for (int i = 0; i < 16; ++i) {
            const int k = i * 16 + wv * 4 + g;                     // 4 rows/instr
            const float4 v = *(const float4*)(fb + (size_t)k * HW + 4 * q);
            float t0 = __shfl_xor(v.x, 32), t1 = __shfl_xor(v.y, 32);
            float t2 = __shfl_xor(v.z, 32), t3 = __shfl_xor(v.w, 32);
            const bool h2 = (g & 2) != 0;
            float p0 = h2 ? t2 : v.x, p1 = h2 ? t3 : v.y;
            float p2 = h2 ? v.z : t0, p3 = h2 ? v.w : t1;
            float u0 = __shfl_xor(p0, 16), u1 = __shfl_xor(p1, 16);
            float u2 = __shfl_xor(p2, 16), u3 = __shfl_xor(p3, 16);
            const bool h1 = (g & 1) != 0;
            float c0 = h1 ? u1 : p0, c1 = h1 ? p1 : u0;
            float c2 = h1 ? u3 : p2, c3 = h1 ? p3 : u2;
            const int k0 = i * 16 + wv * 4;
            uint2 pk;
            pk.x = (unsigned)f2bf(c0) | ((unsigned)f2bf(c1) << 16);
            pk.y = (unsigned)f2bf(c2) | ((unsigned)f2bf(c3) << 16);
            *(uint2*)(smem + fbt_addr(4 * q + g, k0)) = pk;
        }
    }
    __syncthreads();

    f32x4 acc[8];
    #pragma unroll
    for (int m = 0; m < 8; ++m) acc[m] = (f32x4){0.f, 0.f, 0.f, 0.f};
    #pragma unroll
    for (int ks = 0; ks < 8; ++ks) {
        short8 bf = *(const short8*)(smem + fbt_addr(colg, ks * 32 + kg * 8));
        #pragma unroll
        for (int m = 0; m < 8; ++m) {
            short8 af = *(const short8*)(W1a + ((ks * 8 + m) * 64 + ln) * 8);
            acc[m] = __builtin_amdgcn_mfma_f32_16x16x32_bf16(af, bf, acc[m], 0, 0, 0);
        }
    }
    __syncthreads();

    #pragma unroll
    for (int m = 0; m < 8; ++m) {
        float4 bv = *(const float4*)(b1 + m * 16 + kg * 4);
        float v0 = acc[m][0] + bv.x, v1 = acc[m][1] + bv.y;
        float v2 = acc[m][2] + bv.z, v3 = acc[m][3] + bv.w;
        v0 = v0 > 0.f ? v0 : 0.01f * v0;  v1 = v1 > 0.f ? v1 : 0.01f * v1;
        v2 = v2 > 0.f ? v2 : 0.01f * v2;  v3 = v3 > 0.f ? v3 : 0.01f * v3;
        unsigned lo = (unsigned)f2bf(v0) | ((unsigned)f2bf(v1) << 16);
        unsigned hi = (unsigned)f2bf(v2) | ((unsigned)f2bf(v3) << 16);
        *(uint2*)(smem + hbt_addr(colg, m * 16 + kg * 4)) = make_uint2(lo, hi);
    }
    __syncthreads();

    f32x4 a2[5];
    #pragma unroll
    for (int m = 0; m < 5; ++m) a2[m] = (f32x4){0.f, 0.f, 0.f, 0.f};
    #pragma unroll
    for (int ks = 0; ks < 4; ++ks) {
        short8 bf = *(const short8*)(smem + hbt_addr(colg, ks * 32 + kg * 8));
        #pragma unroll
        for (int m = 0; m < 5; ++m) {
            short8 af = *(const short8*)(W2a + ((ks * 5 + m) * 64 + ln) * 8);
            a2[m] = __builtin_amdgcn_mfma_f32_16x16x32_bf16(af, bf, a2[m], 0, 0, 0);
        }
    }
    __syncthreads();

    float* Ot = (float*)smem;
    #pragma unroll
    for (int m = 0; m < 5; ++m) {
        float4 bv = *(const float4*)(b2p + m * 16 + kg * 4);
        #pragma unroll
        for (int i = 0; i < 4; ++i)
            Ot[(m * 16 + kg * 4 + i) * 65 + colg] = a2[m][i] + ((const float*)&bv)[i];
    }
    __syncthreads();

    // epilogue: proposals only; anchors split 2/2/2/3 across waves
    {
        const float* OtC = (const float*)smem;
        const int hw = hw0 + col;
        const float2 g2 = ((const float2*)grid)[(size_t)b * HW + hw];
        const int a_lo = 2 * wv;
        const int a_hi = (wv == 3) ? 9 : 2 * wv + 2;
        for (int a = a_lo; a < a_hi; ++a) {
            float t0 = OtC[(A_ + 4 * a + 0) * 65 + col];
            float t1 = OtC[(A_ + 4 * a + 1) * 65 + col];
            float t2 = OtC[(A_ + 4 * a + 2) * 65 + col];
            float t3 = OtC[(A_ + 4 * a + 3) * 65 + col];
            t0 = fsig(t0) - 0.5f;
            t1 = fsig(t1) - 0.5f;
            size_t odx = (size_t)(b * A_ + a) * HW + hw;
            float aw = anc[2 * a], ah = anc[2 * a + 1];
            float xc = g2.x + t0, yc = g2.y + t1;
            float wn = aw * fexp(t2), hn = ah * fexp(t3);
            f32x4 prop = {xc - 0.5f * wn, yc - 0.5f * hn,
                          xc + 0.5f * wn, yc + 0.5f * hn};
            __builtin_nontemporal_store(prop, (f32x4*)dout + odx);
        }
    }
}

extern "C" void kernel_launch(void* const* d_in, const int* in_sizes, int n_in,
                              void* d_out, int out_size, void* d_ws, size_t ws_size,
                              hipStream_t stream) {
    const float* features    = (const float*)d_in[0];
    const float* grid        = (const float*)d_in[1];
    const float* anc         = (const float*)d_in[2];
    const float* bboxes      = (const float*)d_in[3];
    const float* GT_offsets  = (const float*)d_in[4];
    const float* W1          = (const float*)d_in[6];
    const float* b1          = (const float*)d_in[7];
    const float* W2          = (const float*)d_in[8];
    const float* b2          = (const float*)d_in[9];
    const int*   pos_idx     = (const int*)d_in[10];
    const int*   neg_idx     = (const int*)d_in[11];
    float* out = (float*)d_out;
    float* ws  = (float*)d_ws;

    prep_weights<<<169, 256, 0, stream>>>(W1, W2, b2, ws, out);
    fused_kernel<<<NGRID, 256, 0, stream>>>(features, grid, anc, b1, bboxes,
                                            GT_offsets, pos_idx, neg_idx, ws, out);
}

// Round 11
// 108.552 us; speedup vs baseline: 7.4983x; 1.0954x over previous
//
#include <hip/hip_runtime.h>
#include <math.h>

typedef __attribute__((ext_vector_type(8))) short short8;
typedef __attribute__((ext_vector_type(4))) float f32x4;

#define HW    4096
#define B_    32
#define CIN   256
#define HID   128
#define A_    9
#define NCLS  20
#define M_    4096
#define NBOX  64
#define S_TOT (B_*HW)

// ---- output layout (floats) ----
#define PROP_SIZE (B_*A_*HW*4)
#define IOU_OFF   ((size_t)PROP_SIZE)
#define IOU_SIZE  ((size_t)B_*A_*HW*NBOX)
#define CONF_LOSS_OFF (IOU_OFF + IOU_SIZE)
#define REG_LOSS_OFF  (CONF_LOSS_OFF + 1)
#define CLS_OFF       (CONF_LOSS_OFF + 2)

// ---- workspace layout (float offsets) ----
#define WS_W1A_F 0                          // 32768 ushort (W1, A-frag order [ks][m])
#define WS_W2A_F 16384                      // 10240 ushort (W2 padded to 80 rows, [ks][m])
#define WS_B2P   21504                      // 80 floats (b2 padded)
#define WS_CONF  21632                      // B*A*HW raw conf
#define WS_OFF4  (WS_CONF + B_*A_*HW)       // B*A*HW float4 offsets
#define WS_CLS   (WS_OFF4 + B_*A_*HW*4)     // 20 planes of B*HW raw class scores

#define NCONV 2048
#define NIOU  2304                          // 9216 wave-chunks / 4 waves
#define NBLK  (NCONV + NIOU)                // 4352

__device__ __forceinline__ unsigned short f2bf(float x) {   // RNE float->bf16
    unsigned int u = __float_as_uint(x);
    unsigned int r = (u + 0x7FFFu + ((u >> 16) & 1u)) >> 16;
    return (unsigned short)r;
}
__device__ __forceinline__ float vrcp(float x) {            // v_rcp_f32, ~1ulp
    float r; asm("v_rcp_f32 %0, %1" : "=v"(r) : "v"(x)); return r;
}
__device__ __forceinline__ float vexp2(float x) {           // v_exp_f32 = 2^x
    float r; asm("v_exp_f32 %0, %1" : "=v"(r) : "v"(x)); return r;
}
__device__ __forceinline__ float fexp(float x)  { return vexp2(x * 1.44269504f); }
__device__ __forceinline__ float fsig(float x)  { return vrcp(1.0f + fexp(-x)); }

// LDS byte addr for FbT[col][k] (col<64, k<256, bf16), XOR-swizzled.
// Bank-group G(col) = ((col>>2) + (col&3)*2) & 7 covers all 8 groups both for
// consecutive-col runs (GEMM b128 reads) AND stride-4-col runs (stage b64
// writes, col = 4q+g with g fixed per 16-lane service window). The old
// (col&7) group collapsed the write pattern to 2 groups -> 8-way conflict
// (measured 4.5M SQ_LDS_BANK_CONFLICT cycles, R10).
__device__ __forceinline__ int fbt_addr(int col, int k) {
    int grp = ((col >> 2) + ((col & 3) << 1)) & 7;
    return col * 512 + ((k * 2) ^ (grp << 4));
}
// LDS byte addr for HbT[col][k] (col<64, k<128, bf16) — overlays FbT region.
// Writes are consecutive-col (conflict-free with col&7); reads consecutive.
__device__ __forceinline__ int hbt_addr(int col, int k) {
    return col * 256 + ((k * 2) ^ ((col & 7) << 4));
}

// Pack W1 (128x256) and W2 (65x128 -> 80x128 zero-pad) into MFMA A-fragment order,
// fragment index = ks*NM + m (ks-major: 8KB window shared by the waves via L1).
// A-frag for 16x16x32: lane l holds A[m*16 + (l&15)][ks*32 + (l>>4)*8 + j], j=0..7.
__global__ __launch_bounds__(256) void prep_weights(
    const float* __restrict__ W1, const float* __restrict__ W2,
    const float* __restrict__ b2, float* __restrict__ ws)
{
    int t = blockIdx.x * 256 + threadIdx.x;
    unsigned short* W1a = (unsigned short*)(ws + WS_W1A_F);
    unsigned short* W2a = (unsigned short*)(ws + WS_W2A_F);
    if (t < 32768) {
        int j = t & 7, l = (t >> 3) & 63, f = t >> 9;   // f = ks*8 + m
        int ks = f >> 3, m = f & 7;
        int row = m * 16 + (l & 15);
        int k   = ks * 32 + (l >> 4) * 8 + j;
        W1a[t] = f2bf(W1[row * CIN + k]);
    } else if (t < 32768 + 10240) {
        int u = t - 32768;
        int j = u & 7, l = (u >> 3) & 63, f = u >> 9;   // f = ks*5 + m
        int ks = f / 5, m = f % 5;
        int row = m * 16 + (l & 15);
        int k   = ks * 32 + (l >> 4) * 8 + j;
        W2a[u] = f2bf(row < 65 ? W2[row * HID + k] : 0.0f);
    } else if (t < 32768 + 10240 + 80) {
        int v = t - 43008;
        ws[WS_B2P + v] = (v < 65) ? b2[v] : 0.0f;
    }
}

// Role-split fused kernel: even bids<4096 = conv tile (64 spatial positions),
// odd bids + tail = IoU chunk blocks. No barriers couple the two roles; the
// IoU blocks' NT stores drain while conv blocks sit in staging/MFMA latency.
__global__ __launch_bounds__(256, 4) void fused_kernel(
    const float* __restrict__ features, const float* __restrict__ grid,
    const float* __restrict__ anc,      const float* __restrict__ b1,
    const float* __restrict__ bboxes,
    float* __restrict__ ws,             float* __restrict__ dout)
{
    const int bid = blockIdx.x;
    const int tid = threadIdx.x;
    const int wv  = tid >> 6;
    const int ln  = tid & 63;

    bool is_conv; int idx;
    if (bid < 2 * NCONV) { is_conv = (bid & 1) == 0; idx = bid >> 1; }
    else                 { is_conv = false;          idx = NCONV + (bid - 2 * NCONV); }

    if (!is_conv) {
        // ---- IoU block: 4 waves, wave = one (b, a, 128-hw) chunk ----
        const int cid = idx * 4 + wv;                 // 0..9215
        const int b   = cid / (A_ * 32);
        const int rem = cid % (A_ * 32);
        const int a   = rem / 32;
        const int hw0 = (rem % 32) * 128;
        const int hwi = ln >> 4;
        const int nq  = ln & 15;

        float bx0[4], by0[4], bx2[4], by2[4], areab[4];
        #pragma unroll
        for (int j = 0; j < 4; ++j) {
            const float* bb = bboxes + ((size_t)b * NBOX + nq * 4 + j) * 5;
            bx0[j] = bb[0]; by0[j] = bb[1]; bx2[j] = bb[2]; by2[j] = bb[3];
            areab[j] = (bx2[j] - bx0[j]) * (by2[j] - by0[j]);
        }
        const float hwd = 0.5f * anc[2 * a], hh = 0.5f * anc[2 * a + 1];
        const float ap  = 4.0f * hwd * hh;
        const float2* gp = (const float2*)grid + (size_t)b * HW;
        float* ioub = dout + IOU_OFF + (size_t)(b * A_ + a) * HW * NBOX;
        #pragma unroll 4
        for (int t = 0; t < 32; ++t) {
            const int hw = hw0 + t * 4 + hwi;
            const float2 g = gp[hw];
            f32x4 res;
            #pragma unroll
            for (int j = 0; j < 4; ++j) {
                float dx = fmaxf(fminf(bx2[j] - g.x, hwd) - fmaxf(bx0[j] - g.x, -hwd), 0.0f);
                float dy = fmaxf(fminf(by2[j] - g.y, hh ) - fmaxf(by0[j] - g.y, -hh ), 0.0f);
                float inter = dx * dy;
                res[j] = inter * vrcp(ap + areab[j] - inter);
            }
            // wave store = 1KB contiguous (addr = base + ln*16)
            __builtin_nontemporal_store(
                res, (f32x4*)(ioub + ((size_t)hw) * NBOX + nq * 4));
        }
        return;
    }

    // ---- conv block ----
    __shared__ __align__(16) char smem[32768];   // FbT 32KB; HbT/Ot overlay

    const int s0  = idx * 64;
    const int b   = s0 >> 12;
    const int hw0 = s0 & (HW - 1);
    const int col = tid & 63;
    const int kg  = ln >> 4;           // k-group 0..3
    const int colg = wv * 16 + (ln & 15);

    // ---- stage F tile (256 x 64): float4 loads + in-register 4x4 lane
    // transpose (shfl_xor 32/16 butterfly) -> bf16 -> swizzled FbT ----
    {
        const int g = ln >> 4, q = ln & 15;
        const float* fb = features + (size_t)b * CIN * HW + hw0;
        #pragma unroll
        for (int i = 0; i < 16; ++i) {
            const int k = i * 16 + wv * 4 + g;                     // 4 rows/instr
            const float4 v = *(const float4*)(fb + (size_t)k * HW + 4 * q);
            float t0 = __shfl_xor(v.x, 32), t1 = __shfl_xor(v.y, 32);
            float t2 = __shfl_xor(v.z, 32), t3 = __shfl_xor(v.w, 32);
            const bool h2 = (g & 2) != 0;
            float p0 = h2 ? t2 : v.x, p1 = h2 ? t3 : v.y;
            float p2 = h2 ? v.z : t0, p3 = h2 ? v.w : t1;
            float u0 = __shfl_xor(p0, 16), u1 = __shfl_xor(p1, 16);
            float u2 = __shfl_xor(p2, 16), u3 = __shfl_xor(p3, 16);
            const bool h1 = (g & 1) != 0;
            float c0 = h1 ? u1 : p0, c1 = h1 ? p1 : u0;
            float c2 = h1 ? u3 : p2, c3 = h1 ? p3 : u2;
            const int k0 = i * 16 + wv * 4;
            uint2 pk;
            pk.x = (unsigned)f2bf(c0) | ((unsigned)f2bf(c1) << 16);
            pk.y = (unsigned)f2bf(c2) | ((unsigned)f2bf(c3) << 16);
            *(uint2*)(smem + fbt_addr(4 * q + g, k0)) = pk;
        }
    }
    __syncthreads();

    // ---- GEMM1: hdn[128][64] = W1 @ F ----
    const unsigned short* W1a = (const unsigned short*)(ws + WS_W1A_F);
    f32x4 acc[8];
    #pragma unroll
    for (int m = 0; m < 8; ++m) acc[m] = (f32x4){0.f, 0.f, 0.f, 0.f};
    #pragma unroll
    for (int ks = 0; ks < 8; ++ks) {
        short8 bf = *(const short8*)(smem + fbt_addr(colg, ks * 32 + kg * 8));
        #pragma unroll
        for (int m = 0; m < 8; ++m) {
            short8 af = *(const short8*)(W1a + ((ks * 8 + m) * 64 + ln) * 8);
            acc[m] = __builtin_amdgcn_mfma_f32_16x16x32_bf16(af, bf, acc[m], 0, 0, 0);
        }
    }
    __syncthreads();   // all FbT reads done before HbT overlays the region

    // ---- bias + leaky relu, bf16, write HbT (swizzled, overlays FbT) ----
    #pragma unroll
    for (int m = 0; m < 8; ++m) {
        float4 bv = *(const float4*)(b1 + m * 16 + kg * 4);
        float v0 = acc[m][0] + bv.x, v1 = acc[m][1] + bv.y;
        float v2 = acc[m][2] + bv.z, v3 = acc[m][3] + bv.w;
        v0 = v0 > 0.f ? v0 : 0.01f * v0;  v1 = v1 > 0.f ? v1 : 0.01f * v1;
        v2 = v2 > 0.f ? v2 : 0.01f * v2;  v3 = v3 > 0.f ? v3 : 0.01f * v3;
        unsigned int lo = (unsigned int)f2bf(v0) | ((unsigned int)f2bf(v1) << 16);
        unsigned int hi = (unsigned int)f2bf(v2) | ((unsigned int)f2bf(v3) << 16);
        *(uint2*)(smem + hbt_addr(colg, m * 16 + kg * 4)) = make_uint2(lo, hi);
    }
    __syncthreads();

    // ---- GEMM2: out[80][64] = W2pad @ hdn ----
    const unsigned short* W2a = (const unsigned short*)(ws + WS_W2A_F);
    f32x4 a2[5];
    #pragma unroll
    for (int m = 0; m < 5; ++m) a2[m] = (f32x4){0.f, 0.f, 0.f, 0.f};
    #pragma unroll
    for (int ks = 0; ks < 4; ++ks) {
        short8 bf = *(const short8*)(smem + hbt_addr(colg, ks * 32 + kg * 8));
        #pragma unroll
        for (int m = 0; m < 5; ++m) {
            short8 af = *(const short8*)(W2a + ((ks * 5 + m) * 64 + ln) * 8);
            a2[m] = __builtin_amdgcn_mfma_f32_16x16x32_bf16(af, bf, a2[m], 0, 0, 0);
        }
    }
    __syncthreads();   // all HbT reads done before Ot overlays the region

    // ---- stage out tile to LDS (fp32, stride 65) ----
    float* Ot = (float*)smem;
    const float* b2p = ws + WS_B2P;
    #pragma unroll
    for (int m = 0; m < 5; ++m) {
        float4 bv = *(const float4*)(b2p + m * 16 + kg * 4);
        #pragma unroll
        for (int i = 0; i < 4; ++i)
            Ot[(m * 16 + kg * 4 + i) * 65 + colg] = a2[m][i] + ((const float*)&bv)[i];
    }
    __syncthreads();

    // ---- epilogue: wave 0 conf, waves 1-2 offsets+proposals, wave 3 cls ----
    const float* OtC = (const float*)smem;
    const int hw = hw0 + col;
    if (wv == 0) {
        #pragma unroll
        for (int a = 0; a < A_; ++a)
            ws[WS_CONF + (size_t)(b * A_ + a) * HW + hw] = OtC[a * 65 + col];
    } else if (wv == 3) {
        #pragma unroll
        for (int c = 0; c < NCLS; ++c)
            ws[WS_CLS + (size_t)c * S_TOT + b * HW + hw] = OtC[(45 + c) * 65 + col];
    } else {
        const float2 g2 = ((const float2*)grid)[(size_t)b * HW + hw];
        int a0 = (wv == 1) ? 0 : 4;
        int a1 = (wv == 1) ? 4 : 9;
        for (int a = a0; a < a1; ++a) {
            float t0 = OtC[(A_ + 4 * a + 0) * 65 + col];
            float t1 = OtC[(A_ + 4 * a + 1) * 65 + col];
            float t2 = OtC[(A_ + 4 * a + 2) * 65 + col];
            float t3 = OtC[(A_ + 4 * a + 3) * 65 + col];
            t0 = fsig(t0) - 0.5f;
            t1 = fsig(t1) - 0.5f;
            size_t odx = (size_t)(b * A_ + a) * HW + hw;
            ((float4*)(ws + WS_OFF4))[odx] = make_float4(t0, t1, t2, t3);
            float aw = anc[2 * a], ah = anc[2 * a + 1];
            float xc = g2.x + t0, yc = g2.y + t1;
            float wn = aw * fexp(t2), hn = ah * fexp(t3);
            f32x4 prop = {xc - 0.5f * wn, yc - 0.5f * hn,
                          xc + 0.5f * wn, yc + 0.5f * hn};
            __builtin_nontemporal_store(prop, (f32x4*)dout + odx);
        }
    }
}

// blocks [0,320): class_scores gather; block 320: conf+reg losses.
__global__ __launch_bounds__(256) void tail_kernel(
    const float* __restrict__ ws, const float* __restrict__ GT_offsets,
    const int* __restrict__ pos_idx, const int* __restrict__ neg_idx,
    float* __restrict__ dout)
{
    int tid = threadIdx.x;
    if (blockIdx.x < 320) {
        int t = blockIdx.x * 256 + tid;            // 81920 = 320*256 exactly
        int m = t / NCLS, c = t % NCLS;
        int ip = pos_idx[m];
        int bb = ip / (A_ * HW);
        int hw = ip & (HW - 1);
        dout[CLS_OFF + t] = ws[WS_CLS + (size_t)c * S_TOT + bb * HW + hw];
        return;
    }
    float conf_sum = 0.0f, reg_sum = 0.0f;
    for (int m = tid; m < M_; m += 256) {
        int ip = pos_idx[m], in_ = neg_idx[m];
        float cp = fsig(ws[WS_CONF + ip]);
        float cn = fsig(ws[WS_CONF + in_]);
        conf_sum += (cp - 1.0f) * (cp - 1.0f) + cn * cn;
        float4 off = ((const float4*)(ws + WS_OFF4))[ip];
        float d0 = off.x - GT_offsets[4 * m + 0];
        float d1 = off.y - GT_offsets[4 * m + 1];
        float d2 = off.z - GT_offsets[4 * m + 2];
        float d3 = off.w - GT_offsets[4 * m + 3];
        reg_sum += d0 * d0 + d1 * d1 + d2 * d2 + d3 * d3;
    }
    #pragma unroll
    for (int off = 32; off > 0; off >>= 1) {
        conf_sum += __shfl_down(conf_sum, off);
        reg_sum  += __shfl_down(reg_sum, off);
    }
    __shared__ float rc[4], rr[4];
    int w = tid >> 6;
    if ((tid & 63) == 0) { rc[w] = conf_sum; rr[w] = reg_sum; }
    __syncthreads();
    if (tid == 0) {
        float c = rc[0] + rc[1] + rc[2] + rc[3];
        float r = rr[0] + rr[1] + rr[2] + rr[3];
        dout[CONF_LOSS_OFF] = c / (2.0f * M_);
        dout[REG_LOSS_OFF]  = r / (float)M_;
    }
}

extern "C" void kernel_launch(void* const* d_in, const int* in_sizes, int n_in,
                              void* d_out, int out_size, void* d_ws, size_t ws_size,
                              hipStream_t stream) {
    const float* features    = (const float*)d_in[0];
    const float* grid        = (const float*)d_in[1];
    const float* anc         = (const float*)d_in[2];
    const float* bboxes      = (const float*)d_in[3];
    const float* GT_offsets  = (const float*)d_in[4];
    const float* W1          = (const float*)d_in[6];
    const float* b1          = (const float*)d_in[7];
    const float* W2          = (const float*)d_in[8];
    const float* b2          = (const float*)d_in[9];
    const int*   pos_idx     = (const int*)d_in[10];
    const int*   neg_idx     = (const int*)d_in[11];
    float* out = (float*)d_out;
    float* ws  = (float*)d_ws;

    prep_weights<<<169, 256, 0, stream>>>(W1, W2, b2, ws);
    fused_kernel<<<NBLK, 256, 0, stream>>>(features, grid, anc, b1, bboxes, ws, out);
    tail_kernel<<<321, 256, 0, stream>>>(ws, GT_offsets, pos_idx, neg_idx, out);
}